// Round 1
// 742.982 us; speedup vs baseline: 3.7820x; 3.7820x over previous
//
#include <hip/hip_runtime.h>

#define N_NODES 50000
#define N_EDGES 1000000
#define N_ETYPES 3
#define TOT (N_ETYPES * N_NODES)   // 150000 (etype,node) bins

typedef _Float16 f16x8 __attribute__((ext_vector_type(8)));
typedef float f32x4 __attribute__((ext_vector_type(4)));

// ---------- Kernel 0: W[e][k][n] fp32 -> Wt[e][n][k] fp16 ----------
__global__ void k_prep_w(const float* __restrict__ W, _Float16* __restrict__ Wt) {
    int e  = blockIdx.y;
    int id = blockIdx.x * blockDim.x + threadIdx.x;   // 0..32767
    int k  = id >> 7;
    int n  = id & 127;
    Wt[(size_t)e * 32768 + (size_t)n * 256 + k] =
        (_Float16)W[(size_t)e * 32768 + (size_t)k * 128 + n];
}

// ---------- Kernel 1: Wh[e] = fp16( x @ W[e] + b[e] )  (MFMA, no LDS) ----------
// B (Wt) is 64KB/etype -> L2-resident; fragments read straight from global.
// Fragment maps (m89/m91-verified; previously verified bit-identical vs scalar GEMM):
//   A[m=lane&15][k=quad*8+j], B^T row = lane&15, D: col=lane&15, row=quad*4+reg.
__global__ __launch_bounds__(256) void k_gemm(
    const float* __restrict__ x,             // [N,256] fp32
    const _Float16* __restrict__ Wt,         // [3][128][256] fp16 (W^T)
    const float* __restrict__ b,             // [3][128] fp32
    unsigned short* __restrict__ Wh)         // [3][N][128] fp16 bits
{
    const int e    = blockIdx.y;
    const int tid  = threadIdx.x;
    const int lane = tid & 63;
    const int w    = tid >> 6;       // wave 0..3
    const int q    = lane >> 4;      // quad 0..3
    const int c    = lane & 15;      // m for A, n for B/D
    const int rowBase = blockIdx.x * 256;
    const _Float16* Bt = Wt + (size_t)e * 32768;   // [128][256]

    f32x4 acc[4][8];
    #pragma unroll
    for (int mt = 0; mt < 4; ++mt)
        #pragma unroll
        for (int nt = 0; nt < 8; ++nt)
            acc[mt][nt] = (f32x4){0.f, 0.f, 0.f, 0.f};

    int arow[4];
    #pragma unroll
    for (int mt = 0; mt < 4; ++mt) {
        int r = rowBase + w * 64 + mt * 16 + c;
        arow[mt] = (r < N_NODES) ? r : (N_NODES - 1);   // clamp; discarded at store
    }

    #pragma unroll
    for (int ks = 0; ks < 8; ++ks) {           // K = 256 = 8 * 32
        f16x8 afrag[4];
        #pragma unroll
        for (int mt = 0; mt < 4; ++mt) {
            const float* xp = x + (size_t)arow[mt] * 256 + ks * 32 + q * 8;
            f32x4 lo = *(const f32x4*)xp;
            f32x4 hi = *(const f32x4*)(xp + 4);
            f16x8 af;
            #pragma unroll
            for (int j = 0; j < 4; ++j) {
                af[j]     = (_Float16)lo[j];
                af[j + 4] = (_Float16)hi[j];
            }
            afrag[mt] = af;
        }
        #pragma unroll
        for (int nt = 0; nt < 8; ++nt) {
            f16x8 bfrag = *(const f16x8*)(Bt + (size_t)(nt * 16 + c) * 256 + ks * 32 + q * 8);
            #pragma unroll
            for (int mt = 0; mt < 4; ++mt)
                acc[mt][nt] = __builtin_amdgcn_mfma_f32_16x16x32_f16(
                    afrag[mt], bfrag, acc[mt][nt], 0, 0, 0);
        }
    }

    const size_t whBase = (size_t)e * N_NODES * 128;
    #pragma unroll
    for (int nt = 0; nt < 8; ++nt) {
        float bias = b[e * 128 + nt * 16 + c];
        #pragma unroll
        for (int mt = 0; mt < 4; ++mt) {
            int baseRow = rowBase + w * 64 + mt * 16 + q * 4;
            #pragma unroll
            for (int r = 0; r < 4; ++r) {
                int row = baseRow + r;
                if (row < N_NODES) {
                    float v = acc[mt][nt][r] + bias;
                    Wh[whBase + (size_t)row * 128 + nt * 16 + c] =
                        __builtin_bit_cast(unsigned short, (_Float16)v);
                }
            }
        }
    }
}

// ---------- CSR build: histogram -> scan -> fill ----------
__global__ void k_hist(const int* __restrict__ dst, int* __restrict__ cnt) {
    int e = blockIdx.y;
    int i = blockIdx.x * blockDim.x + threadIdx.x;
    if (i >= N_EDGES) return;
    atomicAdd(&cnt[e * N_NODES + dst[(size_t)e * N_EDGES + i]], 1);
}

// Block-level exclusive scan of 1024 elems; writes local-exclusive to `local`,
// block total to partials[blk].
__global__ __launch_bounds__(1024) void k_scan1(const int* __restrict__ cnt,
                                                int* __restrict__ local,
                                                int* __restrict__ partials) {
    int gid = blockIdx.x * 1024 + threadIdx.x;
    int v = (gid < TOT) ? cnt[gid] : 0;
    int lane = threadIdx.x & 63;
    int wv = threadIdx.x >> 6;
    int s = v;
    #pragma unroll
    for (int d = 1; d < 64; d <<= 1) {
        int t = __shfl_up(s, d);
        if (lane >= d) s += t;
    }
    __shared__ int wsum[16];
    __shared__ int woff[16];
    if (lane == 63) wsum[wv] = s;
    __syncthreads();
    if (threadIdx.x == 0) {
        int a = 0;
        #pragma unroll
        for (int i = 0; i < 16; ++i) { int t = wsum[i]; woff[i] = a; a += t; }
        partials[blockIdx.x] = a;
    }
    __syncthreads();
    int excl = s - v + woff[wv];
    if (gid < TOT) local[gid] = excl;
}

// Exclusive scan of the (<=256) block partials in a single block.
__global__ __launch_bounds__(256) void k_scan2(int* __restrict__ partials, int nb) {
    int tid = threadIdx.x;
    int v = (tid < nb) ? partials[tid] : 0;
    int lane = tid & 63, wv = tid >> 6;
    int s = v;
    #pragma unroll
    for (int d = 1; d < 64; d <<= 1) {
        int t = __shfl_up(s, d);
        if (lane >= d) s += t;
    }
    __shared__ int wsum[4];
    __shared__ int woff[4];
    if (lane == 63) wsum[wv] = s;
    __syncthreads();
    if (tid == 0) {
        int a = 0;
        #pragma unroll
        for (int i = 0; i < 4; ++i) { int t = wsum[i]; woff[i] = a; a += t; }
    }
    __syncthreads();
    int excl = s - v + woff[wv];
    if (tid < nb) partials[tid] = excl;
}

// Add scanned block offsets; init cursor = offsets.
__global__ void k_scan3(int* __restrict__ local, const int* __restrict__ partials,
                        int* __restrict__ cursor) {
    int gid = blockIdx.x * blockDim.x + threadIdx.x;
    if (gid >= TOT) return;
    int o = local[gid] + partials[gid >> 10];
    local[gid] = o;
    cursor[gid] = o;
}

__global__ void k_fill(const int* __restrict__ src, const int* __restrict__ dst,
                       int* __restrict__ cursor, int* __restrict__ nbr) {
    int e = blockIdx.y;
    int i = blockIdx.x * blockDim.x + threadIdx.x;
    if (i >= N_EDGES) return;
    int s = src[(size_t)e * N_EDGES + i];
    int d = dst[(size_t)e * N_EDGES + i];
    int pos = atomicAdd(&cursor[e * N_NODES + d], 1);
    nbr[pos] = s;
}

// ---------- Gather: one wave per (etype,node); mean + transpose fused ----------
// Reads each neighbor's Wh row coalesced (64 lanes x 4B = 256B), accumulates
// fp32 in registers, writes out[n][e][:] once. Wh (38.4MB) is L2/L3-resident.
__global__ __launch_bounds__(256) void k_gather(
    const int* __restrict__ offs, const int* __restrict__ cnt,
    const int* __restrict__ nbr, const unsigned short* __restrict__ Wh,
    float* __restrict__ out)
{
    const int lane = threadIdx.x & 63;
    int wid = blockIdx.x * (blockDim.x >> 6) + (threadIdx.x >> 6);
    if (wid >= TOT) return;
    int e = wid / N_NODES;
    int n = wid - e * N_NODES;
    int beg = offs[wid];
    int d   = cnt[wid];
    int end = beg + d;
    const unsigned* base = (const unsigned*)Wh + (size_t)e * N_NODES * 64; // 64 u32/row
    float a0 = 0.f, a1 = 0.f;
    for (int c0 = beg; c0 < end; c0 += 64) {
        int m = end - c0; if (m > 64) m = 64;
        int idx = (c0 + lane < end) ? nbr[c0 + lane] : 0;   // prefetch ids, break dep chain
        for (int j = 0; j < m; ++j) {
            int s = __shfl(idx, j);
            unsigned u = base[(size_t)s * 64 + lane];
            a0 += (float)__builtin_bit_cast(_Float16, (unsigned short)(u & 0xFFFFu));
            a1 += (float)__builtin_bit_cast(_Float16, (unsigned short)(u >> 16));
        }
    }
    float inv = (d > 0) ? (1.0f / (float)d) : 0.f;
    float2 o;
    o.x = a0 * inv;
    o.y = a1 * inv;
    *(float2*)(out + (size_t)n * 384 + e * 128 + 2 * lane) = o;
}

// ---------- launch ----------
extern "C" void kernel_launch(void* const* d_in, const int* in_sizes, int n_in,
                              void* d_out, int out_size, void* d_ws, size_t ws_size,
                              hipStream_t stream) {
    const float* x    = (const float*)d_in[0];
    const int*   esrc = (const int*)d_in[1];
    const int*   edst = (const int*)d_in[2];
    const float* W    = (const float*)d_in[3];
    const float* bias = (const float*)d_in[4];
    float*       out  = (float*)d_out;            // fp32 output [N,3,128]

    char* ws = (char*)d_ws;
    _Float16*       Wt   = (_Float16*)ws;                         //    196,608 B
    unsigned short* Wh   = (unsigned short*)(ws + 196608);        // 38,400,000 B
    int* cnt     = (int*)(ws + 38596608);                         //    600,000 B
    int* offs    = (int*)(ws + 39196608);                         //    600,000 B
    int* cursor  = (int*)(ws + 39796608);                         //    600,000 B
    int* partials= (int*)(ws + 40396608);                         //      4,096 B
    int* nbr     = (int*)(ws + 40400704);                         // 12,000,000 B

    hipMemsetAsync(cnt, 0, TOT * sizeof(int), stream);

    k_prep_w<<<dim3(128, 3), 256, 0, stream>>>(W, Wt);
    k_gemm<<<dim3(196, 3), 256, 0, stream>>>(x, Wt, bias, Wh);

    const int EB = (N_EDGES + 255) / 256;            // 3907
    k_hist<<<dim3(EB, 3), 256, 0, stream>>>(edst, cnt);
    const int SB = (TOT + 1023) / 1024;              // 147
    k_scan1<<<SB, 1024, 0, stream>>>(cnt, offs, partials);
    k_scan2<<<1, 256, 0, stream>>>(partials, SB);
    k_scan3<<<(TOT + 255) / 256, 256, 0, stream>>>(offs, partials, cursor);
    k_fill<<<dim3(EB, 3), 256, 0, stream>>>(esrc, edst, cursor, nbr);

    k_gather<<<(TOT + 3) / 4, 256, 0, stream>>>(offs, cnt, nbr, Wh, out);
}